// Round 1
// baseline (271.772 us; speedup 1.0000x reference)
//
#include <hip/hip_runtime.h>

// out[b,c,i,j] = x[b, c, 2*i + (idx[b,i,j]>>1), 2*j + (idx[b,i,j]&1)]
// x: (16,64,512,512) f32, idx: (16,256,256) i32, out: (16,64,256,256) f32

#define NB 16
#define NC 64
#define NH 512
#define NW 512
#define HO 256
#define WO 256

__global__ __launch_bounds__(256) void pool_gather_kernel(
    const float* __restrict__ x,
    const int*   __restrict__ idx,
    float*       __restrict__ out)
{
    // One thread per (b, i, jv) where jv indexes 4 consecutive output columns.
    // Thread loops over all 64 channels (idx shared across channels).
    int t  = blockIdx.x * 256 + threadIdx.x;   // 0 .. 16*256*64-1
    int jv = t & 63;                           // Wo/4 = 64
    int i  = (t >> 6) & (HO - 1);              // 0..255
    int b  = t >> 14;                          // 0..15
    int j0 = jv << 2;                          // output col base

    // idx for 4 outputs, reused across all channels
    const int4 id4 = *reinterpret_cast<const int4*>(
        idx + ((size_t)b * HO + (size_t)i) * WO + j0);

    const float* xrow = x + ((size_t)b * NC * NH + (size_t)(2 * i)) * NW + 2 * j0;
    float* orow = out + ((size_t)b * NC * HO + (size_t)i) * WO + j0;

    #pragma unroll 2
    for (int c = 0; c < NC; ++c) {
        const float* p0 = xrow + (size_t)c * (NH * NW);  // row 2i
        const float* p1 = p0 + NW;                       // row 2i+1
        // cols 2*j0 .. 2*j0+7 of both candidate rows (32B per row, coalesced)
        float4 a0 = *reinterpret_cast<const float4*>(p0);
        float4 a1 = *reinterpret_cast<const float4*>(p0 + 4);
        float4 b0 = *reinterpret_cast<const float4*>(p1);
        float4 b1 = *reinterpret_cast<const float4*>(p1 + 4);

        float4 o;
        {   // q=0: cols {0,1} within the 8-float window
            int e = id4.x;
            float lo = (e & 1) ? a0.y : a0.x;
            float hi = (e & 1) ? b0.y : b0.x;
            o.x = (e & 2) ? hi : lo;
        }
        {   // q=1: cols {2,3}
            int e = id4.y;
            float lo = (e & 1) ? a0.w : a0.z;
            float hi = (e & 1) ? b0.w : b0.z;
            o.y = (e & 2) ? hi : lo;
        }
        {   // q=2: cols {4,5}
            int e = id4.z;
            float lo = (e & 1) ? a1.y : a1.x;
            float hi = (e & 1) ? b1.y : b1.x;
            o.z = (e & 2) ? hi : lo;
        }
        {   // q=3: cols {6,7}
            int e = id4.w;
            float lo = (e & 1) ? a1.w : a1.z;
            float hi = (e & 1) ? b1.w : b1.z;
            o.w = (e & 2) ? hi : lo;
        }
        *reinterpret_cast<float4*>(orow + (size_t)c * (HO * WO)) = o;
    }
}

extern "C" void kernel_launch(void* const* d_in, const int* in_sizes, int n_in,
                              void* d_out, int out_size, void* d_ws, size_t ws_size,
                              hipStream_t stream)
{
    const float* x   = (const float*)d_in[0];
    const int*   idx = (const int*)d_in[1];
    float*       out = (float*)d_out;

    const int total_threads = NB * HO * (WO / 4);  // 262144
    pool_gather_kernel<<<total_threads / 256, 256, 0, stream>>>(x, idx, out);
}

// Round 3
// 263.078 us; speedup vs baseline: 1.0330x; 1.0330x over previous
//
#include <hip/hip_runtime.h>

// out[b,c,i,j] = x[b, c, 2*i + (idx[b,i,j]>>1), 2*j + (idx[b,i,j]&1)]
// x: (16,64,512,512) f32, idx: (16,256,256) i32, out: (16,64,256,256) f32

#define NB 16
#define NC 64
#define NH 512
#define NW 512
#define HO 256
#define WO 256
#define CG 4                 // channel groups (threads per (b,i,jv) point)
#define CPT (NC / CG)        // channels per thread = 16

typedef float  f32x4 __attribute__((ext_vector_type(4)));
typedef int    i32x4 __attribute__((ext_vector_type(4)));

__global__ __launch_bounds__(256) void pool_gather_kernel(
    const float* __restrict__ x,
    const int*   __restrict__ idx,
    float*       __restrict__ out)
{
    // Thread owns (cg, b, i, jv): 4 consecutive output columns, 16 channels.
    int t  = blockIdx.x * 256 + threadIdx.x;
    int jv = t & 63;                 // Wo/4 = 64
    int i  = (t >> 6) & (HO - 1);    // 0..255
    int b  = (t >> 14) & (NB - 1);   // 0..15
    int cg = t >> 18;                // 0..3
    int j0 = jv << 2;
    int c0 = cg * CPT;

    // idx for 4 outputs, reused across this thread's 16 channels
    const i32x4 id4 = *reinterpret_cast<const i32x4*>(
        idx + ((size_t)b * HO + (size_t)i) * WO + j0);

    const float* xrow = x + ((size_t)(b * NC + c0) * NH + (size_t)(2 * i)) * NW + 2 * j0;
    float* orow = out + ((size_t)(b * NC + c0) * HO + (size_t)i) * WO + j0;

    #pragma unroll 4
    for (int c = 0; c < CPT; ++c) {
        const float* p0 = xrow + (size_t)c * (NH * NW);  // row 2i
        const float* p1 = p0 + NW;                       // row 2i+1
        // cols 2*j0 .. 2*j0+7 of both candidate rows (32B/row/lane, coalesced;
        // wave covers 2 full contiguous 2KB rows). Streaming -> nontemporal.
        f32x4 a0 = __builtin_nontemporal_load(reinterpret_cast<const f32x4*>(p0));
        f32x4 a1 = __builtin_nontemporal_load(reinterpret_cast<const f32x4*>(p0 + 4));
        f32x4 b0 = __builtin_nontemporal_load(reinterpret_cast<const f32x4*>(p1));
        f32x4 b1 = __builtin_nontemporal_load(reinterpret_cast<const f32x4*>(p1 + 4));

        f32x4 o;
        {   int e = id4.x;                       // cols {0,1} of the window
            float lo = (e & 1) ? a0.y : a0.x;
            float hi = (e & 1) ? b0.y : b0.x;
            o.x = (e & 2) ? hi : lo; }
        {   int e = id4.y;                       // cols {2,3}
            float lo = (e & 1) ? a0.w : a0.z;
            float hi = (e & 1) ? b0.w : b0.z;
            o.y = (e & 2) ? hi : lo; }
        {   int e = id4.z;                       // cols {4,5}
            float lo = (e & 1) ? a1.y : a1.x;
            float hi = (e & 1) ? b1.y : b1.x;
            o.z = (e & 2) ? hi : lo; }
        {   int e = id4.w;                       // cols {6,7}
            float lo = (e & 1) ? a1.w : a1.z;
            float hi = (e & 1) ? b1.w : b1.z;
            o.w = (e & 2) ? hi : lo; }
        __builtin_nontemporal_store(o,
            reinterpret_cast<f32x4*>(orow + (size_t)c * (HO * WO)));
    }
}

extern "C" void kernel_launch(void* const* d_in, const int* in_sizes, int n_in,
                              void* d_out, int out_size, void* d_ws, size_t ws_size,
                              hipStream_t stream)
{
    const float* x   = (const float*)d_in[0];
    const int*   idx = (const int*)d_in[1];
    float*       out = (float*)d_out;

    const int total_threads = NB * HO * (WO / 4) * CG;  // 1,048,576
    pool_gather_kernel<<<total_threads / 256, 256, 0, stream>>>(x, idx, out);
}

// Round 4
// 256.406 us; speedup vs baseline: 1.0599x; 1.0260x over previous
//
#include <hip/hip_runtime.h>

// out[b,c,i,j] = x[b, c, 2*i + (idx[b,i,j]>>1), 2*j + (idx[b,i,j]&1)]
// x: (16,64,512,512) f32, idx: (16,256,256) i32, out: (16,64,256,256) f32

#define NB 16
#define NC 64
#define NH 512
#define NW 512
#define HO 256
#define WO 256
#define CG 4                 // channel groups (threads per (b,i) row point)
#define CPT (NC / CG)        // channels per thread = 16

typedef float f32x4 __attribute__((ext_vector_type(4)));
typedef float f32x2 __attribute__((ext_vector_type(2)));
typedef int   i32x2 __attribute__((ext_vector_type(2)));

__global__ __launch_bounds__(256) void pool_gather_kernel(
    const float* __restrict__ x,
    const int*   __restrict__ idx,
    float*       __restrict__ out)
{
    // Lane l of a wave owns half-windows {l, l+64} of output row i:
    // out cols {2l, 2l+1} and {128+2l, 129+2l}. All vmem instructions are
    // dense contiguous bursts across the wave (1KB x-loads, 512B idx/out).
    int t  = blockIdx.x * 256 + threadIdx.x;
    int l  = t & 63;                 // lane within wave
    int i  = (t >> 6) & (HO - 1);    // 0..255
    int b  = (t >> 14) & (NB - 1);   // 0..15
    int cg = t >> 18;                // 0..3
    int c0 = cg * CPT;

    // idx for this thread's 4 output columns, reused across 16 channels
    const int* ib = idx + ((size_t)b * HO + (size_t)i) * WO;
    const i32x2 eL = *reinterpret_cast<const i32x2*>(ib + 2 * l);        // cols 2l,2l+1
    const i32x2 eH = *reinterpret_cast<const i32x2*>(ib + 128 + 2 * l);  // cols 128+2l,129+2l

    const float* xbase = x + ((size_t)(b * NC + c0) * NH + (size_t)(2 * i)) * NW;
    float* obase = out + ((size_t)(b * NC + c0) * HO + (size_t)i) * WO;

    #pragma unroll 4
    for (int c = 0; c < CPT; ++c) {
        const float* r0 = xbase + (size_t)c * (NH * NW);  // source row 2i
        const float* r1 = r0 + NW;                        // source row 2i+1
        // dense 1KB-per-instruction bursts (lane l at +4l floats)
        f32x4 a  = __builtin_nontemporal_load(reinterpret_cast<const f32x4*>(r0 + 4 * l));
        f32x4 ah = __builtin_nontemporal_load(reinterpret_cast<const f32x4*>(r0 + NW / 2 + 4 * l));
        f32x4 bq = __builtin_nontemporal_load(reinterpret_cast<const f32x4*>(r1 + 4 * l));
        f32x4 bh = __builtin_nontemporal_load(reinterpret_cast<const f32x4*>(r1 + NW / 2 + 4 * l));

        f32x2 oL, oH;
        {   int e = eL.x;  // out col 2l: candidates a.x/a.y/bq.x/bq.y
            oL.x = (e & 1) ? ((e & 2) ? bq.y : a.y) : ((e & 2) ? bq.x : a.x); }
        {   int e = eL.y;  // out col 2l+1: a.z/a.w/bq.z/bq.w
            oL.y = (e & 1) ? ((e & 2) ? bq.w : a.w) : ((e & 2) ? bq.z : a.z); }
        {   int e = eH.x;  // out col 128+2l
            oH.x = (e & 1) ? ((e & 2) ? bh.y : ah.y) : ((e & 2) ? bh.x : ah.x); }
        {   int e = eH.y;  // out col 129+2l
            oH.y = (e & 1) ? ((e & 2) ? bh.w : ah.w) : ((e & 2) ? bh.z : ah.z); }

        float* orow = obase + (size_t)c * (HO * WO);
        __builtin_nontemporal_store(oL, reinterpret_cast<f32x2*>(orow + 2 * l));
        __builtin_nontemporal_store(oH, reinterpret_cast<f32x2*>(orow + 128 + 2 * l));
    }
}

extern "C" void kernel_launch(void* const* d_in, const int* in_sizes, int n_in,
                              void* d_out, int out_size, void* d_ws, size_t ws_size,
                              hipStream_t stream)
{
    const float* x   = (const float*)d_in[0];
    const int*   idx = (const int*)d_in[1];
    float*       out = (float*)d_out;

    const int total_threads = NB * HO * 64 * CG;  // 1,048,576
    pool_gather_kernel<<<total_threads / 256, 256, 0, stream>>>(x, idx, out);
}

// Round 5
// 237.366 us; speedup vs baseline: 1.1449x; 1.0802x over previous
//
#include <hip/hip_runtime.h>

// out[b,c,i,j] = x[b, c, 2*i + (idx[b,i,j]>>1), 2*j + (idx[b,i,j]&1)]
// x: (16,64,512,512) f32, idx: (16,256,256) i32, out: (16,64,256,256) f32

#define NB 16
#define NC 64
#define NH 512
#define NW 512
#define HO 256
#define WO 256
#define CG 4                 // channel groups (threads per (b,i) row point)
#define CPT (NC / CG)        // channels per thread = 16

typedef float f32x4 __attribute__((ext_vector_type(4)));
typedef float f32x2 __attribute__((ext_vector_type(2)));
typedef int   i32x2 __attribute__((ext_vector_type(2)));

// (256,8): pin 8 waves/SIMD (32/CU) -> VGPR <= 64, full occupancy guaranteed.
__global__ __launch_bounds__(256, 8) void pool_gather_kernel(
    const float* __restrict__ x,
    const int*   __restrict__ idx,
    float*       __restrict__ out)
{
    // Lane l of a wave owns half-windows {l, l+64} of output row i:
    // out cols {2l, 2l+1} and {128+2l, 129+2l}. All vmem instructions are
    // dense contiguous bursts across the wave.
    int t  = blockIdx.x * 256 + threadIdx.x;
    int l  = t & 63;                 // lane within wave
    int i  = (t >> 6) & (HO - 1);    // 0..255
    int b  = (t >> 14) & (NB - 1);   // 0..15
    int cg = t >> 18;                // 0..3
    int c0 = cg * CPT;

    // idx for this thread's 4 output columns, reused across 16 channels.
    // Loop-invariant: compiler hoists the v_cmp mask setup out of the loop.
    const int* ib = idx + ((size_t)b * HO + (size_t)i) * WO;
    const i32x2 eL = *reinterpret_cast<const i32x2*>(ib + 2 * l);        // cols 2l,2l+1
    const i32x2 eH = *reinterpret_cast<const i32x2*>(ib + 128 + 2 * l);  // cols 128+2l,129+2l

    // Running pointers (strength-reduced): one 64-bit add per iter each.
    // All 4 x-loads share one base; offsets 0/1024/2048/3072 B fit the
    // 13-bit signed global_load offset immediate.
    const float* p = x + ((size_t)(b * NC + c0) * NH + (size_t)(2 * i)) * NW + 4 * l;
    float* q = out + ((size_t)(b * NC + c0) * HO + (size_t)i) * WO + 2 * l;

    #pragma unroll 4
    for (int c = 0; c < CPT; ++c) {
        // x row 2i: [0,1KB); row 2i half2: [1KB,2KB); row 2i+1: [2KB,3KB)+[3KB,4KB)
        f32x4 a  = __builtin_nontemporal_load(reinterpret_cast<const f32x4*>(p));
        f32x4 ah = __builtin_nontemporal_load(reinterpret_cast<const f32x4*>(p + NW / 2));
        f32x4 bq = __builtin_nontemporal_load(reinterpret_cast<const f32x4*>(p + NW));
        f32x4 bh = __builtin_nontemporal_load(reinterpret_cast<const f32x4*>(p + NW + NW / 2));

        f32x2 oL, oH;
        {   int e = eL.x;  // out col 2l: candidates a.x/a.y/bq.x/bq.y
            oL.x = (e & 1) ? ((e & 2) ? bq.y : a.y) : ((e & 2) ? bq.x : a.x); }
        {   int e = eL.y;  // out col 2l+1: a.z/a.w/bq.z/bq.w
            oL.y = (e & 1) ? ((e & 2) ? bq.w : a.w) : ((e & 2) ? bq.z : a.z); }
        {   int e = eH.x;  // out col 128+2l
            oH.x = (e & 1) ? ((e & 2) ? bh.y : ah.y) : ((e & 2) ? bh.x : ah.x); }
        {   int e = eH.y;  // out col 129+2l
            oH.y = (e & 1) ? ((e & 2) ? bh.w : ah.w) : ((e & 2) ? bh.z : ah.z); }

        // plain (cached) stores — A/B vs nt stores
        *reinterpret_cast<f32x2*>(q)       = oL;
        *reinterpret_cast<f32x2*>(q + 128) = oH;

        p += (size_t)NH * NW;   // next channel plane
        q += HO * WO;
    }
}

extern "C" void kernel_launch(void* const* d_in, const int* in_sizes, int n_in,
                              void* d_out, int out_size, void* d_ws, size_t ws_size,
                              hipStream_t stream)
{
    const float* x   = (const float*)d_in[0];
    const int*   idx = (const int*)d_in[1];
    float*       out = (float*)d_out;

    const int total_threads = NB * HO * 64 * CG;  // 1,048,576
    pool_gather_kernel<<<total_threads / 256, 256, 0, stream>>>(x, idx, out);
}